// Round 14
// baseline (355.425 us; speedup 1.0000x reference)
//
#include <hip/hip_runtime.h>
#include <hip/hip_bf16.h>
#include <math.h>

// Problem constants (fixed by the reference)
#define NN 50000
#define NE 800000
#define NPAD 50048   // 1564 * 32 — tail-free GEMM tiles
#define BCAP 48      // bucket capacity per node; P(Poisson(16) > 48) ~ 5e-11
#define NQB 1564     // qkvs1-role blocks in k_build (32 rows each)
#define NSB 6250     // scatter-role blocks in k_build (128 edges each)

typedef unsigned short u16;
typedef unsigned int u32;
typedef __attribute__((ext_vector_type(8))) short short8;   // 8 bf16 (MFMA A/B frag)
typedef __attribute__((ext_vector_type(4))) float float4v;  // MFMA C/D frag

__device__ __forceinline__ float us2f(u16 u) { return __uint_as_float(((unsigned)u) << 16); }
__device__ __forceinline__ float blo(u32 u) { return __uint_as_float(u << 16); }
__device__ __forceinline__ float bhi(u32 u) { return __uint_as_float(u & 0xffff0000u); }
__device__ __forceinline__ u16 f2us(float f) {   // fp32 -> bf16 RNE
    unsigned x = __float_as_uint(f);
    return (u16)((x + 0x7FFFu + ((x >> 16) & 1u)) >> 16);
}
// tanh-gelu via sigmoid identity: 0.5*(1+tanh(u)) = sigmoid(2u)
__device__ __forceinline__ float gelu_f(float x) {
    float p = x * x;
    float t = x * fmaf(p, 0.0713548162726f, 1.5957691216057308f);  // 2u
    float e = __expf(-t);
    return x * __builtin_amdgcn_rcpf(1.0f + e);
}

// ---- permuted-weight B-frag load: WP holds B-frags contiguous per (tile, kblock) ----
// WP u16 layout: tile*2048 + q*512 + l*8 + j  <=>  W[tile*16 + (l&15)][q*32 + (l>>4)*8 + j]
__device__ __forceinline__ void loadB(const u16* __restrict__ WP, int tile, int l,
                                      short8& b0, short8& b1, short8& b2, short8& b3) {
    const short8* wp = (const short8*)WP + (size_t)tile * 256 + l;
    b0 = wp[0]; b1 = wp[64]; b2 = wp[128]; b3 = wp[192];
}
__device__ __forceinline__ float4v mfma4(const short8 (&B)[4],
                                         const short8 (&A)[4]) {
    float4v acc = {0.f, 0.f, 0.f, 0.f};
    acc = __builtin_amdgcn_mfma_f32_16x16x32_bf16(A[0], B[0], acc, 0, 0, 0);
    acc = __builtin_amdgcn_mfma_f32_16x16x32_bf16(A[1], B[1], acc, 0, 0, 0);
    acc = __builtin_amdgcn_mfma_f32_16x16x32_bf16(A[2], B[2], acc, 0, 0, 0);
    acc = __builtin_amdgcn_mfma_f32_16x16x32_bf16(A[3], B[3], acc, 0, 0, 0);
    return acc;
}
// bf16 + bf16 elementwise (fp32 add, RNE round)
__device__ __forceinline__ short8 addbf(short8 x, short8 y) {
    short8 r;
#pragma unroll
    for (int j = 0; j < 8; ++j) r[j] = (short)f2us(us2f((u16)x[j]) + us2f((u16)y[j]));
    return r;
}

// ---------------- weight fp32 -> bf16, permuted into B-frag order ----------------
// sc: per-entry scale folded at convert time (1/sqrt(32) for Wq1/Wq2).
// Also zeroes the scatter cursor (folds the hipMemsetAsync dispatch).

struct CvtEnt { const float* s; u16* d; int n; float sc; };
struct CvtTab { CvtEnt e[14]; };
__global__ void k_cvt_w(CvtTab tab, int* __restrict__ cursor) {
    for (int i = blockIdx.x * 256 + threadIdx.x; i < NN; i += 112 * 256) cursor[i] = 0;
    CvtEnt E = tab.e[blockIdx.x >> 3];
    int chunk = blockIdx.x & 7;
    int per = E.n >> 3;
    int lo = chunk * per, hi = lo + per;
    for (int o = lo + threadIdx.x; o < hi; o += blockDim.x) {
        int tile = o >> 11;
        int q = (o >> 9) & 3;
        int l = (o >> 3) & 63;
        int j = o & 7;
        int row = tile * 16 + (l & 15);
        int col = q * 32 + (l >> 4) * 8 + j;
        E.d[o] = f2us(E.s[row * 128 + col] * E.sc);
    }
}

// =============== block-shared GEMM chain kernels (2 waves split output tiles) ===============
// 32 rows per BLOCK (128 thr = 2 waves), wave wv computes half the output tiles.
// B-frag loads BATCHED 4 sets deep (64 VGPR in flight) before the MFMA runs —
// launch_bounds(128,2) lifts the 64-VGPR cap that serialized the load chains.
// One shared 32x136 LDS buffer; __syncthreads between write/store phases.

// store 32 rows x 128 u16 from LDS to QKVS section (row stride 512) — 128 threads
__device__ __forceinline__ void storeB32(const u16* buf, u16* dst, int r0, int coff, int tid) {
#pragma unroll
    for (int it = 0; it < 4; ++it) {
        int j = it * 128 + tid;
        int row = j >> 4, col = (j & 15) * 8;
        *(uint4*)(dst + (size_t)(r0 + row) * 512 + coff + col) = *(const uint4*)&buf[row * 136 + col];
    }
}
__device__ __forceinline__ void read_frags(const u16* buf, int m, int kb,
                                           short8& f0, short8& f1, short8& f2, short8& f3) {
    const u16* p = buf + m * 136 + kb * 8;
    f0 = *(const short8*)(p);
    f1 = *(const short8*)(p + 32);
    f2 = *(const short8*)(p + 64);
    f3 = *(const short8*)(p + 96);
}
// stage one tile-pair's accumulators (rows kb*4+r and 16+kb*4+r) at col base cidx
__device__ __forceinline__ void stage2(u16* my, int kb, int cidx, float4v x0, float4v x1) {
#pragma unroll
    for (int r = 0; r < 4; ++r) {
        my[(kb * 4 + r) * 136 + cidx] = f2us(x0[r]);
        my[(16 + kb * 4 + r) * 136 + cidx] = f2us(x1[r]);
    }
}

// shared QKVS-projection tail: q (tiles 0..7), kv interleave (8..23), s (24..31)
// wave wv handles its half of each section's tiles; loads batched per section.
// QKVS row (512 u16): [q 0..127 | kv 128..383 | s 384..511]
// kv entry: k[c] at (c>>2)*8+(c&3), v[c] at +4 (one dwordx4 per lane in conv).
__device__ __forceinline__ void qkvs_tail(const u16* __restrict__ Wq,
                                          const short8 (&H)[2][4], u16* my,
                                          u16* __restrict__ QKVS,
                                          int r0, int tid, int wv, int l, int m, int kb) {
    short8 B[4][4];
    // ---- q (tiles 0..7, wave wv: wv*4..wv*4+3) ----
#pragma unroll
    for (int i = 0; i < 4; ++i) loadB(Wq, wv * 4 + i, l, B[i][0], B[i][1], B[i][2], B[i][3]);
#pragma unroll
    for (int i = 0; i < 4; ++i) {
        int tt = wv * 4 + i;
        stage2(my, kb, tt * 16 + m, mfma4(B[i], H[0]), mfma4(B[i], H[1]));
    }
    __syncthreads();
    storeB32(my, QKVS, r0, 0, tid);
    __syncthreads();
    // ---- kv-lo: k tiles 8..11, v tiles 16..19 (wave wv: 2 of each, batched 4) ----
#pragma unroll
    for (int i = 0; i < 2; ++i) loadB(Wq, 8 + wv * 2 + i, l, B[i][0], B[i][1], B[i][2], B[i][3]);
#pragma unroll
    for (int i = 0; i < 2; ++i) loadB(Wq, 16 + wv * 2 + i, l, B[2 + i][0], B[2 + i][1], B[2 + i][2], B[2 + i][3]);
#pragma unroll
    for (int i = 0; i < 2; ++i) {
        int tk = wv * 2 + i;
        stage2(my, kb, tk * 32 + 8 * (m >> 2) + (m & 3), mfma4(B[i], H[0]), mfma4(B[i], H[1]));
    }
#pragma unroll
    for (int i = 0; i < 2; ++i) {
        int tk = wv * 2 + i;
        stage2(my, kb, tk * 32 + 8 * (m >> 2) + (m & 3) + 4, mfma4(B[2 + i], H[0]), mfma4(B[2 + i], H[1]));
    }
    __syncthreads();
    storeB32(my, QKVS, r0, 128, tid);
    __syncthreads();
    // ---- kv-hi: k tiles 12..15, v tiles 20..23 ----
#pragma unroll
    for (int i = 0; i < 2; ++i) loadB(Wq, 12 + wv * 2 + i, l, B[i][0], B[i][1], B[i][2], B[i][3]);
#pragma unroll
    for (int i = 0; i < 2; ++i) loadB(Wq, 20 + wv * 2 + i, l, B[2 + i][0], B[2 + i][1], B[2 + i][2], B[2 + i][3]);
#pragma unroll
    for (int i = 0; i < 2; ++i) {
        int tk = wv * 2 + i;
        stage2(my, kb, tk * 32 + 8 * (m >> 2) + (m & 3), mfma4(B[i], H[0]), mfma4(B[i], H[1]));
    }
#pragma unroll
    for (int i = 0; i < 2; ++i) {
        int tk = wv * 2 + i;
        stage2(my, kb, tk * 32 + 8 * (m >> 2) + (m & 3) + 4, mfma4(B[2 + i], H[0]), mfma4(B[2 + i], H[1]));
    }
    __syncthreads();
    storeB32(my, QKVS, r0, 256, tid);
    __syncthreads();
    // ---- s (tiles 24..31) ----
#pragma unroll
    for (int i = 0; i < 4; ++i) loadB(Wq, 24 + wv * 4 + i, l, B[i][0], B[i][1], B[i][2], B[i][3]);
#pragma unroll
    for (int i = 0; i < 4; ++i) {
        int tt = wv * 4 + i;
        stage2(my, kb, tt * 16 + m, mfma4(B[i], H[0]), mfma4(B[i], H[1]));
    }
    __syncthreads();
    storeB32(my, QKVS, r0, 384, tid);
}

// ---------------- fused build: layer-1 QKVS GEMM ∪ edge scatter ----------------
// Blocks 0..NQB-1: qkvs1 role — 128 thr, 32 rows/block, tiles split across 2 waves.
// Blocks NQB..NQB+NSB-1: scatter role — 128 edges/block, bucketized rec build.

__global__ __launch_bounds__(128, 2) void k_build(const float* __restrict__ Ain,
                                                  const u16* __restrict__ W,
                                                  u16* __restrict__ QKVS,
                                                  const int* __restrict__ srcv,
                                                  const int* __restrict__ dstv,
                                                  const float* __restrict__ eattr,
                                                  int* __restrict__ cursor,
                                                  int4* __restrict__ rec) {
    __shared__ u16 tile[32 * 136];
    if (blockIdx.x >= NQB) {
        // ---- scatter role ----
        int e = (blockIdx.x - NQB) * 128 + threadIdx.x;
        if (e >= NE) return;
        int dst = dstv[e];
        int pos = atomicAdd(&cursor[dst], 1);
        if (pos >= BCAP) return;   // statistically never
        int4 r;
        r.x = srcv[e];
        r.y = __float_as_int(eattr[e * 3 + 0]);
        r.z = __float_as_int(eattr[e * 3 + 1]);
        r.w = __float_as_int(eattr[e * 3 + 2]);
        rec[(size_t)dst * BCAP + pos] = r;
        return;
    }
    // ---- qkvs1 role ----
    int tid = threadIdx.x;
    int l = tid & 63, wv = tid >> 6, m = l & 15, kb = l >> 4;
    int r0 = blockIdx.x * 32;

    short8 A[2][4];
#pragma unroll
    for (int s = 0; s < 2; ++s) {
        int row = r0 + s * 16 + m;
        const float* ap = Ain + (size_t)row * 128;
        bool ok = row < NN;
#pragma unroll
        for (int i = 0; i < 4; ++i) {
            short8 r;
            if (ok) {
                const float* p = ap + (kb + i * 4) * 8;
                float4 f0 = *(const float4*)p;
                float4 f1 = *(const float4*)(p + 4);
                r[0]=(short)f2us(f0.x); r[1]=(short)f2us(f0.y); r[2]=(short)f2us(f0.z); r[3]=(short)f2us(f0.w);
                r[4]=(short)f2us(f1.x); r[5]=(short)f2us(f1.y); r[6]=(short)f2us(f1.z); r[7]=(short)f2us(f1.w);
            } else {
#pragma unroll
                for (int j = 0; j < 8; ++j) r[j] = 0;
            }
            A[s][i] = r;
        }
    }

    qkvs_tail(W, A, tile, QKVS, r0, tid, wv, l, m, kb);
}

// ---------------- fused MLP + next-layer QKVS ----------------

__global__ __launch_bounds__(128, 2) void k_mlp_qkvs(const u16* __restrict__ Ain,
                                                     const u16* __restrict__ Wm,
                                                     const float* __restrict__ bias1,
                                                     const float* __restrict__ bias2,
                                                     const u16* __restrict__ Wq,
                                                     u16* __restrict__ QKVS) {
    __shared__ u16 t1[32 * 136];
    int tid = threadIdx.x;
    int l = tid & 63, wv = tid >> 6, m = l & 15, kb = l >> 4;
    int r0 = blockIdx.x * 32;

    short8 A[2][4];
#pragma unroll
    for (int s = 0; s < 2; ++s) {
        const short8* arow = (const short8*)(Ain + (size_t)(r0 + s * 16 + m) * 128);
#pragma unroll
        for (int i = 0; i < 4; ++i) A[s][i] = arow[kb + i * 4];
    }
    short8 B[4][4];
    // GEMM1 -> t1 (gelu); wave wv: tiles wv*4..wv*4+3 (loads batched)
#pragma unroll
    for (int i = 0; i < 4; ++i) loadB(Wm, wv * 4 + i, l, B[i][0], B[i][1], B[i][2], B[i][3]);
#pragma unroll
    for (int i = 0; i < 4; ++i) {
        int tt = wv * 4 + i;
        float4v x0 = mfma4(B[i], A[0]);
        float4v x1 = mfma4(B[i], A[1]);
        float bv = bias1[tt * 16 + m];
#pragma unroll
        for (int r = 0; r < 4; ++r) {
            t1[(kb * 4 + r) * 136 + tt * 16 + m] = f2us(gelu_f(x0[r] + bv));
            t1[(16 + kb * 4 + r) * 136 + tt * 16 + m] = f2us(gelu_f(x1[r] + bv));
        }
    }
    __syncthreads();
    short8 C[2][4];
    read_frags(t1, m, kb, C[0][0], C[0][1], C[0][2], C[0][3]);
    read_frags(t1 + 16 * 136, m, kb, C[1][0], C[1][1], C[1][2], C[1][3]);
    __syncthreads();   // reads complete before overwrite
    // GEMM2 -> t1 (gelu, no residual; residual added from regs at h-read)
#pragma unroll
    for (int i = 0; i < 4; ++i) loadB(Wm + 16384, wv * 4 + i, l, B[i][0], B[i][1], B[i][2], B[i][3]);
#pragma unroll
    for (int i = 0; i < 4; ++i) {
        int tt = wv * 4 + i;
        float4v x0 = mfma4(B[i], C[0]);
        float4v x1 = mfma4(B[i], C[1]);
        float bv = bias2[tt * 16 + m];
#pragma unroll
        for (int r = 0; r < 4; ++r) {
            t1[(kb * 4 + r) * 136 + tt * 16 + m] = f2us(gelu_f(x0[r] + bv));
            t1[(16 + kb * 4 + r) * 136 + tt * 16 + m] = f2us(gelu_f(x1[r] + bv));
        }
    }
    __syncthreads();
    // H2 frags = GEMM2 rows + register residual
    short8 H[2][4];
#pragma unroll
    for (int s = 0; s < 2; ++s) {
        short8 f0, f1, f2, f3;
        read_frags(t1 + s * 16 * 136, m, kb, f0, f1, f2, f3);
        H[s][0] = addbf(f0, A[s][0]);
        H[s][1] = addbf(f1, A[s][1]);
        H[s][2] = addbf(f2, A[s][2]);
        H[s][3] = addbf(f3, A[s][3]);
    }
    __syncthreads();

    qkvs_tail(Wq, H, t1, QKVS, r0, tid, wv, l, m, kb);
}

// ---------------- fused MLP + final MLP ----------------

__global__ __launch_bounds__(128, 2) void k_mlp_final(const u16* __restrict__ Ain,
                                                      const u16* __restrict__ Wm,
                                                      const float* __restrict__ bias1,
                                                      const float* __restrict__ bias2,
                                                      const u16* __restrict__ Wf,
                                                      const float* __restrict__ bf1,
                                                      const float* __restrict__ bf2,
                                                      float* __restrict__ outp) {
    __shared__ u16 t1[32 * 136];
    int tid = threadIdx.x;
    int l = tid & 63, wv = tid >> 6, m = l & 15, kb = l >> 4;
    int r0 = blockIdx.x * 32;

    short8 A[2][4];
#pragma unroll
    for (int s = 0; s < 2; ++s) {
        const short8* arow = (const short8*)(Ain + (size_t)(r0 + s * 16 + m) * 128);
#pragma unroll
        for (int i = 0; i < 4; ++i) A[s][i] = arow[kb + i * 4];
    }
    short8 B[4][4];
#pragma unroll
    for (int i = 0; i < 4; ++i) loadB(Wm, wv * 4 + i, l, B[i][0], B[i][1], B[i][2], B[i][3]);
#pragma unroll
    for (int i = 0; i < 4; ++i) {
        int tt = wv * 4 + i;
        float4v x0 = mfma4(B[i], A[0]);
        float4v x1 = mfma4(B[i], A[1]);
        float bv = bias1[tt * 16 + m];
#pragma unroll
        for (int r = 0; r < 4; ++r) {
            t1[(kb * 4 + r) * 136 + tt * 16 + m] = f2us(gelu_f(x0[r] + bv));
            t1[(16 + kb * 4 + r) * 136 + tt * 16 + m] = f2us(gelu_f(x1[r] + bv));
        }
    }
    __syncthreads();
    short8 C[2][4];
    read_frags(t1, m, kb, C[0][0], C[0][1], C[0][2], C[0][3]);
    read_frags(t1 + 16 * 136, m, kb, C[1][0], C[1][1], C[1][2], C[1][3]);
    __syncthreads();
#pragma unroll
    for (int i = 0; i < 4; ++i) loadB(Wm + 16384, wv * 4 + i, l, B[i][0], B[i][1], B[i][2], B[i][3]);
#pragma unroll
    for (int i = 0; i < 4; ++i) {
        int tt = wv * 4 + i;
        float4v x0 = mfma4(B[i], C[0]);
        float4v x1 = mfma4(B[i], C[1]);
        float bv = bias2[tt * 16 + m];
#pragma unroll
        for (int r = 0; r < 4; ++r) {
            t1[(kb * 4 + r) * 136 + tt * 16 + m] = f2us(gelu_f(x0[r] + bv));
            t1[(16 + kb * 4 + r) * 136 + tt * 16 + m] = f2us(gelu_f(x1[r] + bv));
        }
    }
    __syncthreads();
    short8 H[2][4];
#pragma unroll
    for (int s = 0; s < 2; ++s) {
        short8 f0, f1, f2, f3;
        read_frags(t1 + s * 16 * 136, m, kb, f0, f1, f2, f3);
        H[s][0] = addbf(f0, A[s][0]);
        H[s][1] = addbf(f1, A[s][1]);
        H[s][2] = addbf(f2, A[s][2]);
        H[s][3] = addbf(f3, A[s][3]);
    }
    __syncthreads();
    // G3 = gelu(H4@Wf1+bf1) -> t1
#pragma unroll
    for (int i = 0; i < 4; ++i) loadB(Wf, wv * 4 + i, l, B[i][0], B[i][1], B[i][2], B[i][3]);
#pragma unroll
    for (int i = 0; i < 4; ++i) {
        int tt = wv * 4 + i;
        float4v x0 = mfma4(B[i], H[0]);
        float4v x1 = mfma4(B[i], H[1]);
        float bv = bf1[tt * 16 + m];
#pragma unroll
        for (int r = 0; r < 4; ++r) {
            t1[(kb * 4 + r) * 136 + tt * 16 + m] = f2us(gelu_f(x0[r] + bv));
            t1[(16 + kb * 4 + r) * 136 + tt * 16 + m] = f2us(gelu_f(x1[r] + bv));
        }
    }
    __syncthreads();
    short8 F[2][4];
    read_frags(t1, m, kb, F[0][0], F[0][1], F[0][2], F[0][3]);
    read_frags(t1 + 16 * 136, m, kb, F[1][0], F[1][1], F[1][2], F[1][3]);
    __syncthreads();
    // G4 = gelu(G3@Wf2+bf2), 64 cols -> t1 (4 tiles, wave wv: wv*2..wv*2+1)
#pragma unroll
    for (int i = 0; i < 2; ++i) loadB(Wf + 16384, wv * 2 + i, l, B[i][0], B[i][1], B[i][2], B[i][3]);
#pragma unroll
    for (int i = 0; i < 2; ++i) {
        int tt = wv * 2 + i;
        float4v x0 = mfma4(B[i], F[0]);
        float4v x1 = mfma4(B[i], F[1]);
        float bv = bf2[tt * 16 + m];
#pragma unroll
        for (int r = 0; r < 4; ++r) {
            t1[(kb * 4 + r) * 136 + tt * 16 + m] = f2us(gelu_f(x0[r] + bv));
            t1[(16 + kb * 4 + r) * 136 + tt * 16 + m] = f2us(gelu_f(x1[r] + bv));
        }
    }
    __syncthreads();
    // output: 32 rows x 64 cols fp32, 128 threads x 2 iters
#pragma unroll
    for (int it = 0; it < 2; ++it) {
        int j = it * 128 + tid;
        int row = j >> 3, col = (j & 7) * 8;
        int grow = r0 + row;
        if (grow < NN) {
            uint4 pk = *(const uint4*)&t1[row * 136 + col];
            const u16* pv = (const u16*)&pk;
            float* po = outp + (size_t)grow * 64 + col;
            float4 o0 = {us2f(pv[0]), us2f(pv[1]), us2f(pv[2]), us2f(pv[3])};
            float4 o1 = {us2f(pv[4]), us2f(pv[5]), us2f(pv[6]), us2f(pv[7])};
            *(float4*)po = o0;
            *(float4*)(po + 4) = o1;
        }
    }
}

// ---------------- TransformerConv aggregation: 2 edges/wave, 4 cols/lane ----------------
// 1 wave per node (4 nodes/block). Lanes 0-31 handle even-offset edges, 32-63 odd.
// Lane li: head=li>>3, group p4=li&7 -> cols c0=head*32+p4*4 .. +3.
// kv gather: one dwordx4/lane = {k[c0..c0+3], v[c0..c0+3]}; head dot = 3 shfl rounds.
// q pre-scaled by 1/sqrt(32) at weight-convert time. Buckets: edge list for node n
// is rec[n*BCAP .. n*BCAP+cnt), cnt from cursor[n].
// No-max softmax (exp clamp 80); halves combined exactly via shfl_xor(·,32).

__global__ __launch_bounds__(256) void k_conv(const int* __restrict__ cursor,
                                              const int4* __restrict__ rec,
                                              const u16* __restrict__ qkvs,
                                              const float* __restrict__ We,
                                              u16* __restrict__ out) {
    int n = blockIdx.x * 4 + (threadIdx.x >> 6);
    int l = threadIdx.x & 63;
    int half = l >> 5;
    int li = l & 31;
    int c0 = (li >> 3) * 32 + (li & 7) * 4;
    const u16* qrow = qkvs + (size_t)n * 512;
    uint2 qu = *(const uint2*)(qrow + c0);          // pre-scaled q
    uint2 su = *(const uint2*)(qrow + 384 + c0);    // skip row — prefetched early
    float q0 = blo(qu.x), q1 = bhi(qu.x), q2 = blo(qu.y), q3 = bhi(qu.y);
    // g_j = sum over head cols of q_c * We[c][j] (8-lane reduce within head).
    float g0, g1, g2;
    {
        const float* wp = We + c0 * 3;
        g0 = fmaf(q3, wp[9],  fmaf(q2, wp[6], fmaf(q1, wp[3], q0 * wp[0])));
        g1 = fmaf(q3, wp[10], fmaf(q2, wp[7], fmaf(q1, wp[4], q0 * wp[1])));
        g2 = fmaf(q3, wp[11], fmaf(q2, wp[8], fmaf(q1, wp[5], q0 * wp[2])));
#pragma unroll
        for (int d = 1; d <= 4; d <<= 1) {
            g0 += __shfl_xor(g0, d);
            g1 += __shfl_xor(g1, d);
            g2 += __shfl_xor(g2, d);
        }
    }
    int cntall = min(cursor[n], BCAP);
    int base = n * BCAP;
    float ss = 0.f, o0 = 0.f, o1 = 0.f, o2 = 0.f, o3 = 0.f, S0 = 0.f, S1 = 0.f, S2 = 0.f;
    int kvoff = 128 + li * 8;   // (c0>>2)*8 == li*8

    auto edge = [&](int4 r, uint4 kv) {
        float part = fmaf(q3, bhi(kv.y), fmaf(q2, blo(kv.y), fmaf(q1, bhi(kv.x), q0 * blo(kv.x))));
        part += __shfl_xor(part, 1);
        part += __shfl_xor(part, 2);
        part += __shfl_xor(part, 4);
        float ea0 = __int_as_float(r.y), ea1 = __int_as_float(r.z), ea2 = __int_as_float(r.w);
        float alpha = fmaf(ea2, g2, fmaf(ea1, g1, fmaf(ea0, g0, part)));
        float p = __expf(fminf(alpha, 80.f));
        o0 = fmaf(p, blo(kv.z), o0);
        o1 = fmaf(p, bhi(kv.z), o1);
        o2 = fmaf(p, blo(kv.w), o2);
        o3 = fmaf(p, bhi(kv.w), o3);
        ss += p;
        S0 = fmaf(p, ea0, S0);
        S1 = fmaf(p, ea1, S1);
        S2 = fmaf(p, ea2, S2);
    };

    // this half processes edges base+half, base+half+2, ...
    int e = base + half;
    int cnt = (half < cntall) ? ((cntall - half + 1) >> 1) : 0;
    if (cnt & 1) {
        int4 r = rec[e];
        uint4 kv = *(const uint4*)(qkvs + (size_t)r.x * 512 + kvoff);
        edge(r, kv);
        e += 2;
    }
    for (int i = 0; i < (cnt >> 1); ++i, e += 4) {
        int4 ra = rec[e], rb = rec[e + 2];
        uint4 kva = *(const uint4*)(qkvs + (size_t)ra.x * 512 + kvoff);
        uint4 kvb = *(const uint4*)(qkvs + (size_t)rb.x * 512 + kvoff);
        edge(ra, kva);
        edge(rb, kvb);
    }
    // combine the two half-wave partials (exact additive)
    o0 += __shfl_xor(o0, 32);
    o1 += __shfl_xor(o1, 32);
    o2 += __shfl_xor(o2, 32);
    o3 += __shfl_xor(o3, 32);
    ss += __shfl_xor(ss, 32);
    S0 += __shfl_xor(S0, 32);
    S1 += __shfl_xor(S1, 32);
    S2 += __shfl_xor(S2, 32);
    if (half == 0) {
        float inv = __builtin_amdgcn_rcpf(fmaxf(ss, 1e-16f));
        const float* wp = We + c0 * 3;   // L1-hot reload (kept out of loop registers)
        o0 = fmaf(wp[2],  S2, fmaf(wp[1],  S1, fmaf(wp[0], S0, o0)));
        o1 = fmaf(wp[5],  S2, fmaf(wp[4],  S1, fmaf(wp[3], S0, o1)));
        o2 = fmaf(wp[8],  S2, fmaf(wp[7],  S1, fmaf(wp[6], S0, o2)));
        o3 = fmaf(wp[11], S2, fmaf(wp[10], S1, fmaf(wp[9], S0, o3)));
        float r0v = fmaf(o0, inv, blo(su.x));
        float r1v = fmaf(o1, inv, bhi(su.x));
        float r2v = fmaf(o2, inv, blo(su.y));
        float r3v = fmaf(o3, inv, bhi(su.y));
        uint2 ou;
        ou.x = (u32)f2us(r0v) | ((u32)f2us(r1v) << 16);
        ou.y = (u32)f2us(r2v) | ((u32)f2us(r3v) << 16);
        *(uint2*)(out + (size_t)n * 128 + c0) = ou;
    }
}

// ---------------- launcher ----------------

extern "C" void kernel_launch(void* const* d_in, const int* in_sizes, int n_in,
                              void* d_out, int out_size, void* d_ws, size_t ws_size,
                              hipStream_t stream) {
    const float* x = (const float*)d_in[0];
    const int* ei = (const int*)d_in[1];
    const float* eattr = (const float*)d_in[2];
    const float* Wq1 = (const float*)d_in[3];
    const float* Wk1 = (const float*)d_in[4];
    const float* Wv1 = (const float*)d_in[5];
    const float* We1 = (const float*)d_in[6];
    const float* Ws1 = (const float*)d_in[7];
    const float* M1a = (const float*)d_in[8];
    const float* b1a = (const float*)d_in[9];
    const float* M1b = (const float*)d_in[10];
    const float* b1b = (const float*)d_in[11];
    const float* Wq2 = (const float*)d_in[12];
    const float* Wk2 = (const float*)d_in[13];
    const float* Wv2 = (const float*)d_in[14];
    const float* We2 = (const float*)d_in[15];
    const float* Ws2 = (const float*)d_in[16];
    const float* M2a = (const float*)d_in[17];
    const float* b2a = (const float*)d_in[18];
    const float* M2b = (const float*)d_in[19];
    const float* b2b = (const float*)d_in[20];
    const float* Wf1 = (const float*)d_in[21];
    const float* bf1 = (const float*)d_in[22];
    const float* Wf2 = (const float*)d_in[23];
    const float* bf2 = (const float*)d_in[24];

    char* ws = (char*)d_ws;
    size_t off = 0;
    auto alloc = [&](size_t bytes) -> void* {
        void* p = ws + off;
        off = (off + bytes + 255) & ~(size_t)255;
        return p;
    };
    int* cursor = (int*)alloc((size_t)NN * 4);
    int4* rec = (int4*)alloc((size_t)NN * BCAP * 16);      // 38.4 MB buckets
    u16* QKVS = (u16*)alloc((size_t)NPAD * 512 * 2);
    u16* Ha = (u16*)alloc((size_t)NPAD * 128 * 2);
    // weight order: [Wq1 Wk1 Wv1 Ws1][Wq2 Wk2 Wv2 Ws2][M1a M1b][M2a M2b][Wf1 Wf2]
    u16* WB[14];
    const int wsz[14] = {16384, 16384, 16384, 16384, 16384, 16384, 16384,
                         16384, 16384, 16384, 16384, 16384, 16384, 8192};
    for (int i = 0; i < 14; ++i) WB[i] = (u16*)alloc((size_t)wsz[i] * 2);

    const int* srcv = ei;
    const int* dstv = ei + NE;

    CvtTab tab;
    const float* wsrc[14] = {Wq1, Wk1, Wv1, Ws1, Wq2, Wk2, Wv2, Ws2,
                             M1a, M1b, M2a, M2b, Wf1, Wf2};
    const float SC = 0.17677669529663687f;   // 1/sqrt(32) folded into Wq1/Wq2
    for (int i = 0; i < 14; ++i) {
        tab.e[i].s = wsrc[i];
        tab.e[i].d = WB[i];
        tab.e[i].n = wsz[i];
        tab.e[i].sc = (i == 0 || i == 4) ? SC : 1.0f;
    }
    // weight convert + cursor zero (one launch)
    k_cvt_w<<<112, 256, 0, stream>>>(tab, cursor);

    dim3 blk(128);
    dim3 grd(NQB);         // 1564 blocks x 32 rows
    dim3 gconv(NN / 4);    // 12500

    // fused: layer-1 QKVS projection (blocks 0..1563) ∪ edge scatter (1564..7813)
    k_build<<<NQB + NSB, blk, 0, stream>>>(x, WB[0], QKVS, srcv, dstv, eattr, cursor, rec);
    k_conv<<<gconv, dim3(256), 0, stream>>>(cursor, rec, QKVS, We1, Ha);        // H1 = Ha
    // MLP1 + layer-2 QKVS (H2 never hits HBM)
    k_mlp_qkvs<<<grd, blk, 0, stream>>>(Ha, WB[8], b1a, b1b, WB[4], QKVS);
    k_conv<<<gconv, dim3(256), 0, stream>>>(cursor, rec, QKVS, We2, Ha);        // H3 = Ha
    // MLP2 + final MLP (H4 never hits HBM)
    k_mlp_final<<<grd, blk, 0, stream>>>(Ha, WB[10], b2a, b2b, WB[12], bf1, bf2, (float*)d_out);
}

// Round 15
// 338.924 us; speedup vs baseline: 1.0487x; 1.0487x over previous
//
#include <hip/hip_runtime.h>
#include <hip/hip_bf16.h>
#include <math.h>

// Problem constants (fixed by the reference)
#define NN 50000
#define NE 800000
#define NPAD 50048   // 1564 * 32 — tail-free GEMM tiles
#define BCAP 48      // bucket capacity per node; P(Poisson(16) > 48) ~ 5e-11
#define NQB 1564     // qkvs1-role blocks in k_build (32 rows each)
#define NSB 6250     // scatter-role blocks in k_build (128 edges each)

typedef unsigned short u16;
typedef unsigned int u32;
typedef __attribute__((ext_vector_type(8))) short short8;   // 8 bf16 (MFMA A/B frag)
typedef __attribute__((ext_vector_type(4))) float float4v;  // MFMA C/D frag

__device__ __forceinline__ float us2f(u16 u) { return __uint_as_float(((unsigned)u) << 16); }
__device__ __forceinline__ float blo(u32 u) { return __uint_as_float(u << 16); }
__device__ __forceinline__ float bhi(u32 u) { return __uint_as_float(u & 0xffff0000u); }
__device__ __forceinline__ u16 f2us(float f) {   // fp32 -> bf16 RNE
    unsigned x = __float_as_uint(f);
    return (u16)((x + 0x7FFFu + ((x >> 16) & 1u)) >> 16);
}
// tanh-gelu via sigmoid identity: 0.5*(1+tanh(u)) = sigmoid(2u)
__device__ __forceinline__ float gelu_f(float x) {
    float p = x * x;
    float t = x * fmaf(p, 0.0713548162726f, 1.5957691216057308f);  // 2u
    float e = __expf(-t);
    return x * __builtin_amdgcn_rcpf(1.0f + e);
}

// ---- permuted-weight B-frag load: WP holds B-frags contiguous per (tile, kblock) ----
// WP u16 layout: tile*2048 + q*512 + l*8 + j  <=>  W[tile*16 + (l&15)][q*32 + (l>>4)*8 + j]
__device__ __forceinline__ void loadB(const u16* __restrict__ WP, int tile, int l,
                                      short8& b0, short8& b1, short8& b2, short8& b3) {
    const short8* wp = (const short8*)WP + (size_t)tile * 256 + l;
    b0 = wp[0]; b1 = wp[64]; b2 = wp[128]; b3 = wp[192];
}
__device__ __forceinline__ float4v mfma4(short8 b0, short8 b1, short8 b2, short8 b3,
                                         short8 a0, short8 a1, short8 a2, short8 a3) {
    float4v acc = {0.f, 0.f, 0.f, 0.f};
    acc = __builtin_amdgcn_mfma_f32_16x16x32_bf16(a0, b0, acc, 0, 0, 0);
    acc = __builtin_amdgcn_mfma_f32_16x16x32_bf16(a1, b1, acc, 0, 0, 0);
    acc = __builtin_amdgcn_mfma_f32_16x16x32_bf16(a2, b2, acc, 0, 0, 0);
    acc = __builtin_amdgcn_mfma_f32_16x16x32_bf16(a3, b3, acc, 0, 0, 0);
    return acc;
}
// bf16 + bf16 elementwise (fp32 add, RNE round)
__device__ __forceinline__ short8 addbf(short8 x, short8 y) {
    short8 r;
#pragma unroll
    for (int j = 0; j < 8; ++j) r[j] = (short)f2us(us2f((u16)x[j]) + us2f((u16)y[j]));
    return r;
}

// ---------------- weight fp32 -> bf16, permuted into B-frag order ----------------
// sc: per-entry scale folded at convert time (1/sqrt(32) for Wq1/Wq2).
// Also zeroes the scatter cursor (folds the hipMemsetAsync dispatch).

struct CvtEnt { const float* s; u16* d; int n; float sc; };
struct CvtTab { CvtEnt e[14]; };
__global__ void k_cvt_w(CvtTab tab, int* __restrict__ cursor) {
    for (int i = blockIdx.x * 256 + threadIdx.x; i < NN; i += 112 * 256) cursor[i] = 0;
    CvtEnt E = tab.e[blockIdx.x >> 3];
    int chunk = blockIdx.x & 7;
    int per = E.n >> 3;
    int lo = chunk * per, hi = lo + per;
    for (int o = lo + threadIdx.x; o < hi; o += blockDim.x) {
        int tile = o >> 11;
        int q = (o >> 9) & 3;
        int l = (o >> 3) & 63;
        int j = o & 7;
        int row = tile * 16 + (l & 15);
        int col = q * 32 + (l >> 4) * 8 + j;
        E.d[o] = f2us(E.s[row * 128 + col] * E.sc);
    }
}

// =============== block-shared GEMM chain kernels (double-buffered staging) ===============
// 32 rows per BLOCK (128 thr = 2 waves), wave wv computes half the output tiles.
// TWO 32x136 LDS buffers alternate per section: compute(buf0); sync;
// {store(buf0) || compute(buf1)}; sync; ... — halves the barrier count and
// overlaps every global-store drain (syncthreads = vmcnt(0)) with the next
// section's B-loads + MFMAs. Arithmetic order identical -> bit-identical output.

// store 32 rows x 128 u16 from LDS to QKVS section (row stride 512) — 128 threads
__device__ __forceinline__ void storeB32(const u16* buf, u16* dst, int r0, int coff, int tid) {
#pragma unroll
    for (int it = 0; it < 4; ++it) {
        int j = it * 128 + tid;
        int row = j >> 4, col = (j & 15) * 8;
        *(uint4*)(dst + (size_t)(r0 + row) * 512 + coff + col) = *(const uint4*)&buf[row * 136 + col];
    }
}
__device__ __forceinline__ void read_frags(const u16* buf, int m, int kb,
                                           short8& f0, short8& f1, short8& f2, short8& f3) {
    const u16* p = buf + m * 136 + kb * 8;
    f0 = *(const short8*)(p);
    f1 = *(const short8*)(p + 32);
    f2 = *(const short8*)(p + 64);
    f3 = *(const short8*)(p + 96);
}
// stage one tile-pair's accumulators (rows kb*4+r and 16+kb*4+r) at col base cidx
__device__ __forceinline__ void stage2(u16* my, int kb, int cidx, float4v x0, float4v x1) {
#pragma unroll
    for (int r = 0; r < 4; ++r) {
        my[(kb * 4 + r) * 136 + cidx] = f2us(x0[r]);
        my[(16 + kb * 4 + r) * 136 + cidx] = f2us(x1[r]);
    }
}
// compute wave wv's share of a q/s-style section (4 tiles) into buf
__device__ __forceinline__ void sec_qs(const u16* __restrict__ Wq, int tbase,
                                       const short8 (&H)[2][4], u16* buf,
                                       int wv, int l, int m, int kb) {
#pragma unroll
    for (int i = 0; i < 4; ++i) {
        int tt = wv * 4 + i;
        short8 b0, b1, b2, b3;
        loadB(Wq, tbase + tt, l, b0, b1, b2, b3);
        float4v x0 = mfma4(b0, b1, b2, b3, H[0][0], H[0][1], H[0][2], H[0][3]);
        float4v x1 = mfma4(b0, b1, b2, b3, H[1][0], H[1][1], H[1][2], H[1][3]);
        stage2(buf, kb, tt * 16 + m, x0, x1);
    }
}
// compute wave wv's share of a kv half-section (2 k-tiles + 2 v-tiles) into buf
__device__ __forceinline__ void sec_kv(const u16* __restrict__ Wq, int kbase, int vbase,
                                       const short8 (&H)[2][4], u16* buf,
                                       int wv, int l, int m, int kb) {
#pragma unroll
    for (int i = 0; i < 2; ++i) {
        int tk = wv * 2 + i;
        short8 b0, b1, b2, b3;
        loadB(Wq, kbase + tk, l, b0, b1, b2, b3);
        float4v x0 = mfma4(b0, b1, b2, b3, H[0][0], H[0][1], H[0][2], H[0][3]);
        float4v x1 = mfma4(b0, b1, b2, b3, H[1][0], H[1][1], H[1][2], H[1][3]);
        stage2(buf, kb, tk * 32 + 8 * (m >> 2) + (m & 3), x0, x1);
    }
#pragma unroll
    for (int i = 0; i < 2; ++i) {
        int tk = wv * 2 + i;
        short8 b0, b1, b2, b3;
        loadB(Wq, vbase + tk, l, b0, b1, b2, b3);
        float4v x0 = mfma4(b0, b1, b2, b3, H[0][0], H[0][1], H[0][2], H[0][3]);
        float4v x1 = mfma4(b0, b1, b2, b3, H[1][0], H[1][1], H[1][2], H[1][3]);
        stage2(buf, kb, tk * 32 + 8 * (m >> 2) + (m & 3) + 4, x0, x1);
    }
}

// shared QKVS-projection tail, double-buffered:
// q->buf0 | sync | store q + kv-lo->buf1 | sync | store kv-lo + kv-hi->buf0 |
// sync | store kv-hi + s->buf1 | sync | store s.   4 barriers (was 10).
// QKVS row (512 u16): [q 0..127 | kv 128..383 | s 384..511]
// kv entry: k[c] at (c>>2)*8+(c&3), v[c] at +4 (one dwordx4 per lane in conv).
__device__ __forceinline__ void qkvs_tail(const u16* __restrict__ Wq,
                                          const short8 (&H)[2][4],
                                          u16* buf0, u16* buf1,
                                          u16* __restrict__ QKVS,
                                          int r0, int tid, int wv, int l, int m, int kb) {
    sec_qs(Wq, 0, H, buf0, wv, l, m, kb);                 // q
    __syncthreads();
    storeB32(buf0, QKVS, r0, 0, tid);
    sec_kv(Wq, 8, 16, H, buf1, wv, l, m, kb);             // kv-lo
    __syncthreads();
    storeB32(buf1, QKVS, r0, 128, tid);
    sec_kv(Wq, 12, 20, H, buf0, wv, l, m, kb);            // kv-hi
    __syncthreads();
    storeB32(buf0, QKVS, r0, 256, tid);
    sec_qs(Wq, 24, H, buf1, wv, l, m, kb);                // s
    __syncthreads();
    storeB32(buf1, QKVS, r0, 384, tid);
}

// ---------------- fused build: layer-1 QKVS GEMM ∪ edge scatter ----------------
// Blocks 0..NQB-1: qkvs1 role — 128 thr, 32 rows/block, tiles split across 2 waves.
// Blocks NQB..NQB+NSB-1: scatter role — 128 edges/block, bucketized rec build.

__global__ __launch_bounds__(128, 4) void k_build(const float* __restrict__ Ain,
                                                  const u16* __restrict__ W,
                                                  u16* __restrict__ QKVS,
                                                  const int* __restrict__ srcv,
                                                  const int* __restrict__ dstv,
                                                  const float* __restrict__ eattr,
                                                  int* __restrict__ cursor,
                                                  int4* __restrict__ rec) {
    __shared__ u16 tile[2][32 * 136];
    if (blockIdx.x >= NQB) {
        // ---- scatter role ----
        int e = (blockIdx.x - NQB) * 128 + threadIdx.x;
        if (e >= NE) return;
        int dst = dstv[e];
        int pos = atomicAdd(&cursor[dst], 1);
        if (pos >= BCAP) return;   // statistically never
        int4 r;
        r.x = srcv[e];
        r.y = __float_as_int(eattr[e * 3 + 0]);
        r.z = __float_as_int(eattr[e * 3 + 1]);
        r.w = __float_as_int(eattr[e * 3 + 2]);
        rec[(size_t)dst * BCAP + pos] = r;
        return;
    }
    // ---- qkvs1 role ----
    int tid = threadIdx.x;
    int l = tid & 63, wv = tid >> 6, m = l & 15, kb = l >> 4;
    int r0 = blockIdx.x * 32;

    short8 A[2][4];
#pragma unroll
    for (int s = 0; s < 2; ++s) {
        int row = r0 + s * 16 + m;
        const float* ap = Ain + (size_t)row * 128;
        bool ok = row < NN;
#pragma unroll
        for (int i = 0; i < 4; ++i) {
            short8 r;
            if (ok) {
                const float* p = ap + (kb + i * 4) * 8;
                float4 f0 = *(const float4*)p;
                float4 f1 = *(const float4*)(p + 4);
                r[0]=(short)f2us(f0.x); r[1]=(short)f2us(f0.y); r[2]=(short)f2us(f0.z); r[3]=(short)f2us(f0.w);
                r[4]=(short)f2us(f1.x); r[5]=(short)f2us(f1.y); r[6]=(short)f2us(f1.z); r[7]=(short)f2us(f1.w);
            } else {
#pragma unroll
                for (int j = 0; j < 8; ++j) r[j] = 0;
            }
            A[s][i] = r;
        }
    }

    qkvs_tail(W, A, tile[0], tile[1], QKVS, r0, tid, wv, l, m, kb);
}

// ---------------- fused MLP + next-layer QKVS ----------------

__global__ __launch_bounds__(128, 4) void k_mlp_qkvs(const u16* __restrict__ Ain,
                                                     const u16* __restrict__ Wm,
                                                     const float* __restrict__ bias1,
                                                     const float* __restrict__ bias2,
                                                     const u16* __restrict__ Wq,
                                                     u16* __restrict__ QKVS) {
    __shared__ u16 t1[2][32 * 136];
    int tid = threadIdx.x;
    int l = tid & 63, wv = tid >> 6, m = l & 15, kb = l >> 4;
    int r0 = blockIdx.x * 32;

    short8 A[2][4];
#pragma unroll
    for (int s = 0; s < 2; ++s) {
        const short8* arow = (const short8*)(Ain + (size_t)(r0 + s * 16 + m) * 128);
#pragma unroll
        for (int i = 0; i < 4; ++i) A[s][i] = arow[kb + i * 4];
    }
    // GEMM1 -> buf0 (gelu); wave wv: tiles wv*4..wv*4+3
#pragma unroll
    for (int i = 0; i < 4; ++i) {
        int tt = wv * 4 + i;
        short8 b0, b1, b2, b3;
        loadB(Wm, tt, l, b0, b1, b2, b3);
        float4v x0 = mfma4(b0, b1, b2, b3, A[0][0], A[0][1], A[0][2], A[0][3]);
        float4v x1 = mfma4(b0, b1, b2, b3, A[1][0], A[1][1], A[1][2], A[1][3]);
        float bv = bias1[tt * 16 + m];
#pragma unroll
        for (int r = 0; r < 4; ++r) {
            t1[0][(kb * 4 + r) * 136 + tt * 16 + m] = f2us(gelu_f(x0[r] + bv));
            t1[0][(16 + kb * 4 + r) * 136 + tt * 16 + m] = f2us(gelu_f(x1[r] + bv));
        }
    }
    __syncthreads();
    short8 C[2][4];
    read_frags(t1[0], m, kb, C[0][0], C[0][1], C[0][2], C[0][3]);
    read_frags(t1[0] + 16 * 136, m, kb, C[1][0], C[1][1], C[1][2], C[1][3]);
    // GEMM2 -> buf1 (gelu) — no sync needed, different buffer
#pragma unroll
    for (int i = 0; i < 4; ++i) {
        int tt = wv * 4 + i;
        short8 b0, b1, b2, b3;
        loadB(Wm + 16384, tt, l, b0, b1, b2, b3);
        float4v x0 = mfma4(b0, b1, b2, b3, C[0][0], C[0][1], C[0][2], C[0][3]);
        float4v x1 = mfma4(b0, b1, b2, b3, C[1][0], C[1][1], C[1][2], C[1][3]);
        float bv = bias2[tt * 16 + m];
#pragma unroll
        for (int r = 0; r < 4; ++r) {
            t1[1][(kb * 4 + r) * 136 + tt * 16 + m] = f2us(gelu_f(x0[r] + bv));
            t1[1][(16 + kb * 4 + r) * 136 + tt * 16 + m] = f2us(gelu_f(x1[r] + bv));
        }
    }
    __syncthreads();
    // H2 frags = GEMM2 rows (buf1) + register residual
    short8 H[2][4];
#pragma unroll
    for (int s = 0; s < 2; ++s) {
        short8 f0, f1, f2, f3;
        read_frags(t1[1] + s * 16 * 136, m, kb, f0, f1, f2, f3);
        H[s][0] = addbf(f0, A[s][0]);
        H[s][1] = addbf(f1, A[s][1]);
        H[s][2] = addbf(f2, A[s][2]);
        H[s][3] = addbf(f3, A[s][3]);
    }
    // tail sec0 writes buf0 (C reads drained at last sync); H reads precede next sync
    qkvs_tail(Wq, H, t1[0], t1[1], QKVS, r0, tid, wv, l, m, kb);
}

// ---------------- fused MLP + final MLP ----------------

__global__ __launch_bounds__(128, 4) void k_mlp_final(const u16* __restrict__ Ain,
                                                      const u16* __restrict__ Wm,
                                                      const float* __restrict__ bias1,
                                                      const float* __restrict__ bias2,
                                                      const u16* __restrict__ Wf,
                                                      const float* __restrict__ bf1,
                                                      const float* __restrict__ bf2,
                                                      float* __restrict__ outp) {
    __shared__ u16 t1[2][32 * 136];
    int tid = threadIdx.x;
    int l = tid & 63, wv = tid >> 6, m = l & 15, kb = l >> 4;
    int r0 = blockIdx.x * 32;

    short8 A[2][4];
#pragma unroll
    for (int s = 0; s < 2; ++s) {
        const short8* arow = (const short8*)(Ain + (size_t)(r0 + s * 16 + m) * 128);
#pragma unroll
        for (int i = 0; i < 4; ++i) A[s][i] = arow[kb + i * 4];
    }
    // GEMM1 -> buf0
#pragma unroll
    for (int i = 0; i < 4; ++i) {
        int tt = wv * 4 + i;
        short8 b0, b1, b2, b3;
        loadB(Wm, tt, l, b0, b1, b2, b3);
        float4v x0 = mfma4(b0, b1, b2, b3, A[0][0], A[0][1], A[0][2], A[0][3]);
        float4v x1 = mfma4(b0, b1, b2, b3, A[1][0], A[1][1], A[1][2], A[1][3]);
        float bv = bias1[tt * 16 + m];
#pragma unroll
        for (int r = 0; r < 4; ++r) {
            t1[0][(kb * 4 + r) * 136 + tt * 16 + m] = f2us(gelu_f(x0[r] + bv));
            t1[0][(16 + kb * 4 + r) * 136 + tt * 16 + m] = f2us(gelu_f(x1[r] + bv));
        }
    }
    __syncthreads();
    short8 C[2][4];
    read_frags(t1[0], m, kb, C[0][0], C[0][1], C[0][2], C[0][3]);
    read_frags(t1[0] + 16 * 136, m, kb, C[1][0], C[1][1], C[1][2], C[1][3]);
    // GEMM2 -> buf1
#pragma unroll
    for (int i = 0; i < 4; ++i) {
        int tt = wv * 4 + i;
        short8 b0, b1, b2, b3;
        loadB(Wm + 16384, tt, l, b0, b1, b2, b3);
        float4v x0 = mfma4(b0, b1, b2, b3, C[0][0], C[0][1], C[0][2], C[0][3]);
        float4v x1 = mfma4(b0, b1, b2, b3, C[1][0], C[1][1], C[1][2], C[1][3]);
        float bv = bias2[tt * 16 + m];
#pragma unroll
        for (int r = 0; r < 4; ++r) {
            t1[1][(kb * 4 + r) * 136 + tt * 16 + m] = f2us(gelu_f(x0[r] + bv));
            t1[1][(16 + kb * 4 + r) * 136 + tt * 16 + m] = f2us(gelu_f(x1[r] + bv));
        }
    }
    __syncthreads();
    short8 H[2][4];
#pragma unroll
    for (int s = 0; s < 2; ++s) {
        short8 f0, f1, f2, f3;
        read_frags(t1[1] + s * 16 * 136, m, kb, f0, f1, f2, f3);
        H[s][0] = addbf(f0, A[s][0]);
        H[s][1] = addbf(f1, A[s][1]);
        H[s][2] = addbf(f2, A[s][2]);
        H[s][3] = addbf(f3, A[s][3]);
    }
    // G3 = gelu(H4@Wf1+bf1) -> buf0 (C reads drained at last sync)
#pragma unroll
    for (int i = 0; i < 4; ++i) {
        int tt = wv * 4 + i;
        short8 b0, b1, b2, b3;
        loadB(Wf, tt, l, b0, b1, b2, b3);
        float4v x0 = mfma4(b0, b1, b2, b3, H[0][0], H[0][1], H[0][2], H[0][3]);
        float4v x1 = mfma4(b0, b1, b2, b3, H[1][0], H[1][1], H[1][2], H[1][3]);
        float bv = bf1[tt * 16 + m];
#pragma unroll
        for (int r = 0; r < 4; ++r) {
            t1[0][(kb * 4 + r) * 136 + tt * 16 + m] = f2us(gelu_f(x0[r] + bv));
            t1[0][(16 + kb * 4 + r) * 136 + tt * 16 + m] = f2us(gelu_f(x1[r] + bv));
        }
    }
    __syncthreads();
    short8 F[2][4];
    read_frags(t1[0], m, kb, F[0][0], F[0][1], F[0][2], F[0][3]);
    read_frags(t1[0] + 16 * 136, m, kb, F[1][0], F[1][1], F[1][2], F[1][3]);
    // G4 = gelu(G3@Wf2+bf2), 64 cols -> buf1 (4 tiles, wave wv: wv*2..wv*2+1)
#pragma unroll
    for (int i = 0; i < 2; ++i) {
        int tt = wv * 2 + i;
        short8 b0, b1, b2, b3;
        loadB(Wf + 16384, tt, l, b0, b1, b2, b3);
        float4v x0 = mfma4(b0, b1, b2, b3, F[0][0], F[0][1], F[0][2], F[0][3]);
        float4v x1 = mfma4(b0, b1, b2, b3, F[1][0], F[1][1], F[1][2], F[1][3]);
        float bv = bf2[tt * 16 + m];
#pragma unroll
        for (int r = 0; r < 4; ++r) {
            t1[1][(kb * 4 + r) * 136 + tt * 16 + m] = f2us(gelu_f(x0[r] + bv));
            t1[1][(16 + kb * 4 + r) * 136 + tt * 16 + m] = f2us(gelu_f(x1[r] + bv));
        }
    }
    __syncthreads();
    // output: 32 rows x 64 cols fp32, 128 threads x 2 iters (from buf1)
#pragma unroll
    for (int it = 0; it < 2; ++it) {
        int j = it * 128 + tid;
        int row = j >> 3, col = (j & 7) * 8;
        int grow = r0 + row;
        if (grow < NN) {
            uint4 pk = *(const uint4*)&t1[1][row * 136 + col];
            const u16* pv = (const u16*)&pk;
            float* po = outp + (size_t)grow * 64 + col;
            float4 o0 = {us2f(pv[0]), us2f(pv[1]), us2f(pv[2]), us2f(pv[3])};
            float4 o1 = {us2f(pv[4]), us2f(pv[5]), us2f(pv[6]), us2f(pv[7])};
            *(float4*)po = o0;
            *(float4*)(po + 4) = o1;
        }
    }
}

// ---------------- TransformerConv aggregation: 2 edges/wave, 4 cols/lane ----------------
// 1 wave per node (4 nodes/block). Lanes 0-31 handle even-offset edges, 32-63 odd.
// Lane li: head=li>>3, group p4=li&7 -> cols c0=head*32+p4*4 .. +3.
// kv gather: one dwordx4/lane = {k[c0..c0+3], v[c0..c0+3]}; head dot = 3 shfl rounds.
// q pre-scaled by 1/sqrt(32) at weight-convert time. Buckets: edge list for node n
// is rec[n*BCAP .. n*BCAP+cnt), cnt from cursor[n].
// No-max softmax (exp clamp 80); halves combined exactly via shfl_xor(·,32).

__global__ __launch_bounds__(256) void k_conv(const int* __restrict__ cursor,
                                              const int4* __restrict__ rec,
                                              const u16* __restrict__ qkvs,
                                              const float* __restrict__ We,
                                              u16* __restrict__ out) {
    int n = blockIdx.x * 4 + (threadIdx.x >> 6);
    int l = threadIdx.x & 63;
    int half = l >> 5;
    int li = l & 31;
    int c0 = (li >> 3) * 32 + (li & 7) * 4;
    const u16* qrow = qkvs + (size_t)n * 512;
    uint2 qu = *(const uint2*)(qrow + c0);          // pre-scaled q
    uint2 su = *(const uint2*)(qrow + 384 + c0);    // skip row — prefetched early
    float q0 = blo(qu.x), q1 = bhi(qu.x), q2 = blo(qu.y), q3 = bhi(qu.y);
    // g_j = sum over head cols of q_c * We[c][j] (8-lane reduce within head).
    float g0, g1, g2;
    {
        const float* wp = We + c0 * 3;
        g0 = fmaf(q3, wp[9],  fmaf(q2, wp[6], fmaf(q1, wp[3], q0 * wp[0])));
        g1 = fmaf(q3, wp[10], fmaf(q2, wp[7], fmaf(q1, wp[4], q0 * wp[1])));
        g2 = fmaf(q3, wp[11], fmaf(q2, wp[8], fmaf(q1, wp[5], q0 * wp[2])));
#pragma unroll
        for (int d = 1; d <= 4; d <<= 1) {
            g0 += __shfl_xor(g0, d);
            g1 += __shfl_xor(g1, d);
            g2 += __shfl_xor(g2, d);
        }
    }
    int cntall = min(cursor[n], BCAP);
    int base = n * BCAP;
    float ss = 0.f, o0 = 0.f, o1 = 0.f, o2 = 0.f, o3 = 0.f, S0 = 0.f, S1 = 0.f, S2 = 0.f;
    int kvoff = 128 + li * 8;   // (c0>>2)*8 == li*8

    auto edge = [&](int4 r, uint4 kv) {
        float part = fmaf(q3, bhi(kv.y), fmaf(q2, blo(kv.y), fmaf(q1, bhi(kv.x), q0 * blo(kv.x))));
        part += __shfl_xor(part, 1);
        part += __shfl_xor(part, 2);
        part += __shfl_xor(part, 4);
        float ea0 = __int_as_float(r.y), ea1 = __int_as_float(r.z), ea2 = __int_as_float(r.w);
        float alpha = fmaf(ea2, g2, fmaf(ea1, g1, fmaf(ea0, g0, part)));
        float p = __expf(fminf(alpha, 80.f));
        o0 = fmaf(p, blo(kv.z), o0);
        o1 = fmaf(p, bhi(kv.z), o1);
        o2 = fmaf(p, blo(kv.w), o2);
        o3 = fmaf(p, bhi(kv.w), o3);
        ss += p;
        S0 = fmaf(p, ea0, S0);
        S1 = fmaf(p, ea1, S1);
        S2 = fmaf(p, ea2, S2);
    };

    // this half processes edges base+half, base+half+2, ...
    int e = base + half;
    int cnt = (half < cntall) ? ((cntall - half + 1) >> 1) : 0;
    if (cnt & 1) {
        int4 r = rec[e];
        uint4 kv = *(const uint4*)(qkvs + (size_t)r.x * 512 + kvoff);
        edge(r, kv);
        e += 2;
    }
    for (int i = 0; i < (cnt >> 1); ++i, e += 4) {
        int4 ra = rec[e], rb = rec[e + 2];
        uint4 kva = *(const uint4*)(qkvs + (size_t)ra.x * 512 + kvoff);
        uint4 kvb = *(const uint4*)(qkvs + (size_t)rb.x * 512 + kvoff);
        edge(ra, kva);
        edge(rb, kvb);
    }
    // combine the two half-wave partials (exact additive)
    o0 += __shfl_xor(o0, 32);
    o1 += __shfl_xor(o1, 32);
    o2 += __shfl_xor(o2, 32);
    o3 += __shfl_xor(o3, 32);
    ss += __shfl_xor(ss, 32);
    S0 += __shfl_xor(S0, 32);
    S1 += __shfl_xor(S1, 32);
    S2 += __shfl_xor(S2, 32);
    if (half == 0) {
        float inv = __builtin_amdgcn_rcpf(fmaxf(ss, 1e-16f));
        const float* wp = We + c0 * 3;   // L1-hot reload (kept out of loop registers)
        o0 = fmaf(wp[2],  S2, fmaf(wp[1],  S1, fmaf(wp[0], S0, o0)));
        o1 = fmaf(wp[5],  S2, fmaf(wp[4],  S1, fmaf(wp[3], S0, o1)));
        o2 = fmaf(wp[8],  S2, fmaf(wp[7],  S1, fmaf(wp[6], S0, o2)));
        o3 = fmaf(wp[11], S2, fmaf(wp[10], S1, fmaf(wp[9], S0, o3)));
        float r0v = fmaf(o0, inv, blo(su.x));
        float r1v = fmaf(o1, inv, bhi(su.x));
        float r2v = fmaf(o2, inv, blo(su.y));
        float r3v = fmaf(o3, inv, bhi(su.y));
        uint2 ou;
        ou.x = (u32)f2us(r0v) | ((u32)f2us(r1v) << 16);
        ou.y = (u32)f2us(r2v) | ((u32)f2us(r3v) << 16);
        *(uint2*)(out + (size_t)n * 128 + c0) = ou;
    }
}

// ---------------- launcher ----------------

extern "C" void kernel_launch(void* const* d_in, const int* in_sizes, int n_in,
                              void* d_out, int out_size, void* d_ws, size_t ws_size,
                              hipStream_t stream) {
    const float* x = (const float*)d_in[0];
    const int* ei = (const int*)d_in[1];
    const float* eattr = (const float*)d_in[2];
    const float* Wq1 = (const float*)d_in[3];
    const float* Wk1 = (const float*)d_in[4];
    const float* Wv1 = (const float*)d_in[5];
    const float* We1 = (const float*)d_in[6];
    const float* Ws1 = (const float*)d_in[7];
    const float* M1a = (const float*)d_in[8];
    const float* b1a = (const float*)d_in[9];
    const float* M1b = (const float*)d_in[10];
    const float* b1b = (const float*)d_in[11];
    const float* Wq2 = (const float*)d_in[12];
    const float* Wk2 = (const float*)d_in[13];
    const float* Wv2 = (const float*)d_in[14];
    const float* We2 = (const float*)d_in[15];
    const float* Ws2 = (const float*)d_in[16];
    const float* M2a = (const float*)d_in[17];
    const float* b2a = (const float*)d_in[18];
    const float* M2b = (const float*)d_in[19];
    const float* b2b = (const float*)d_in[20];
    const float* Wf1 = (const float*)d_in[21];
    const float* bf1 = (const float*)d_in[22];
    const float* Wf2 = (const float*)d_in[23];
    const float* bf2 = (const float*)d_in[24];

    char* ws = (char*)d_ws;
    size_t off = 0;
    auto alloc = [&](size_t bytes) -> void* {
        void* p = ws + off;
        off = (off + bytes + 255) & ~(size_t)255;
        return p;
    };
    int* cursor = (int*)alloc((size_t)NN * 4);
    int4* rec = (int4*)alloc((size_t)NN * BCAP * 16);      // 38.4 MB buckets
    u16* QKVS = (u16*)alloc((size_t)NPAD * 512 * 2);
    u16* Ha = (u16*)alloc((size_t)NPAD * 128 * 2);
    // weight order: [Wq1 Wk1 Wv1 Ws1][Wq2 Wk2 Wv2 Ws2][M1a M1b][M2a M2b][Wf1 Wf2]
    u16* WB[14];
    const int wsz[14] = {16384, 16384, 16384, 16384, 16384, 16384, 16384,
                         16384, 16384, 16384, 16384, 16384, 16384, 8192};
    for (int i = 0; i < 14; ++i) WB[i] = (u16*)alloc((size_t)wsz[i] * 2);

    const int* srcv = ei;
    const int* dstv = ei + NE;

    CvtTab tab;
    const float* wsrc[14] = {Wq1, Wk1, Wv1, Ws1, Wq2, Wk2, Wv2, Ws2,
                             M1a, M1b, M2a, M2b, Wf1, Wf2};
    const float SC = 0.17677669529663687f;   // 1/sqrt(32) folded into Wq1/Wq2
    for (int i = 0; i < 14; ++i) {
        tab.e[i].s = wsrc[i];
        tab.e[i].d = WB[i];
        tab.e[i].n = wsz[i];
        tab.e[i].sc = (i == 0 || i == 4) ? SC : 1.0f;
    }
    // weight convert + cursor zero (one launch)
    k_cvt_w<<<112, 256, 0, stream>>>(tab, cursor);

    dim3 blk(128);
    dim3 grd(NQB);         // 1564 blocks x 32 rows
    dim3 gconv(NN / 4);    // 12500

    // fused: layer-1 QKVS projection (blocks 0..1563) ∪ edge scatter (1564..7813)
    k_build<<<NQB + NSB, blk, 0, stream>>>(x, WB[0], QKVS, srcv, dstv, eattr, cursor, rec);
    k_conv<<<gconv, dim3(256), 0, stream>>>(cursor, rec, QKVS, We1, Ha);        // H1 = Ha
    // MLP1 + layer-2 QKVS (H2 never hits HBM)
    k_mlp_qkvs<<<grd, blk, 0, stream>>>(Ha, WB[8], b1a, b1b, WB[4], QKVS);
    k_conv<<<gconv, dim3(256), 0, stream>>>(cursor, rec, QKVS, We2, Ha);        // H3 = Ha
    // MLP2 + final MLP (H4 never hits HBM)
    k_mlp_final<<<grd, blk, 0, stream>>>(Ha, WB[10], b2a, b2b, WB[12], bf1, bf2, (float*)d_out);
}